// Round 1
// baseline (165.851 us; speedup 1.0000x reference)
//
#include <hip/hip_runtime.h>
#include <hip/hip_bf16.h>

#define BETA_LOG2E 14.426950408889634f   // 10 * log2(e)
#define EPSN 1e-6f

typedef __bf16 bf16x8 __attribute__((ext_vector_type(8)));
typedef float  f32x4  __attribute__((ext_vector_type(4)));

static __device__ inline unsigned short f2bf(float f) {
    __hip_bfloat16 h = __float2bfloat16(f);
    return __builtin_bit_cast(unsigned short, h);
}
static __device__ inline float bf2f(unsigned short u) {
    unsigned int b = ((unsigned int)u) << 16;
    return __builtin_bit_cast(float, b);
}

// ---------------------------------------------------------------------------
// Kernel 1 v2: L2-normalize over C, transpose [b][c][n] -> [b][n][c], bf16.
// Tile: 64 n x 256 c per block. grid 512: idx>>8 selects tensor, then b x ntile.
// Vectorized: f32x4 global loads, b128 LDS writes/reads (16B-block XOR swizzle
// s = cb ^ (n>>2) keeps reads conflict-free), coalesced 512B row stores.
// Numerics match v1: raw value rounded to bf16, then scaled and re-rounded.
// ---------------------------------------------------------------------------
__global__ __launch_bounds__(256) void k_norm_transpose(
    const float* __restrict__ f0, const float* __restrict__ f1,
    unsigned short* __restrict__ aT, unsigned short* __restrict__ bT)
{
    __shared__ unsigned short tile[64 * 256];  // [n][c] raw bf16, swizzled 16B blocks
    __shared__ float partial[16][64];
    __shared__ float inv_l[64];

    int idx   = blockIdx.x;
    int which = idx >> 8;
    int rem   = idx & 255;
    int b     = rem >> 6;
    int n0    = (rem & 63) * 64;
    const float* src = which ? f1 : f0;
    unsigned short* dst = which ? bT : aT;

    int t  = threadIdx.x;
    int nq = t & 15;    // 16 quads of 4 n  -> 64 n
    int cg = t >> 4;    // 16 groups of 16 c -> 256 c

    const float* sp = src + ((size_t)(b * 256 + cg * 16)) * 4096 + n0 + nq * 4;

    f32x4 ss = {0.f, 0.f, 0.f, 0.f};
#pragma unroll
    for (int ch2 = 0; ch2 < 2; ++ch2) {
        unsigned int pk[4][4];   // [j = n sub-row][4 uints = 8 bf16 over c]
#pragma unroll
        for (int i = 0; i < 8; ++i) {
            f32x4 v = *reinterpret_cast<const f32x4*>(sp + (ch2 * 8 + i) * 4096);
            ss += v * v;
#pragma unroll
            for (int j = 0; j < 4; ++j) {
                unsigned int h = f2bf(v[j]);
                if (i & 1) pk[j][i >> 1] |= h << 16;
                else       pk[j][i >> 1]  = h;
            }
        }
        int cb = cg * 2 + ch2;   // 16B block index within row [0,32)
#pragma unroll
        for (int j = 0; j < 4; ++j) {
            int n = nq * 4 + j;
            int s = cb ^ nq;     // nq == n>>2
            *reinterpret_cast<uint4*>(&tile[n * 256 + s * 8]) =
                *reinterpret_cast<const uint4*>(pk[j]);
        }
    }
    *reinterpret_cast<f32x4*>(&partial[cg][nq * 4]) = ss;
    __syncthreads();
    if (t < 64) {
        float s = 0.f;
#pragma unroll
        for (int k = 0; k < 16; ++k) s += partial[k][t];
        inv_l[t] = 1.0f / fmaxf(sqrtf(s), EPSN);
    }
    __syncthreads();

    // write out: each iter covers 8 n rows x 32 blocks of 16B (512B/row, coalesced)
#pragma unroll
    for (int it = 0; it < 8; ++it) {
        int n  = it * 8 + (t >> 5);
        int cb = t & 31;
        int s  = cb ^ (n >> 2);
        uint4 v = *reinterpret_cast<const uint4*>(&tile[n * 256 + s * 8]);
        float inv = inv_l[n];
        unsigned int o[4];
#pragma unroll
        for (int k = 0; k < 4; ++k) {
            unsigned int u = (&v.x)[k];
            unsigned short lo = f2bf(bf2f((unsigned short)(u & 0xffffu)) * inv);
            unsigned short hi = f2bf(bf2f((unsigned short)(u >> 16)) * inv);
            o[k] = (unsigned int)lo | ((unsigned int)hi << 16);
        }
        *reinterpret_cast<uint4*>(&dst[((size_t)(b * 4096 + n0 + n)) * 256 + cb * 8]) =
            *reinterpret_cast<const uint4*>(o);
    }
}

// ---------------------------------------------------------------------------
// Kernel 2: flash cosine-sim + online (fixed-offset) softmax stats.
// 1024 blocks = 4 batch x 32 qtile(128q) x 8 keysplit(512k) -> 4 blocks/CU
// (was 2; occupancy was the binding constraint). 4 waves/block, 32 q/wave.
// Epilogue: ky is constant per 64-key chunk -> Sy accumulated from per-chunk
// Zc; running max kept on pre-exp scores (Sm), exponentiated once at the end.
// stats[q][ks] = {Z, Sx, Sy, Pmax}
// ---------------------------------------------------------------------------
__global__ __launch_bounds__(256, 4) void k_flash(
    const unsigned short* __restrict__ aT, const unsigned short* __restrict__ bT,
    float* __restrict__ stats)
{
    __shared__ unsigned short kbuf[64 * 272];  // 64 keys x 272 halfwords (544 B)

    int idx   = blockIdx.x;
    int xcd   = idx & 7;                 // XCD swizzle: batch -> 2 XCDs
    int batch = xcd >> 1;
    int sub   = ((idx >> 3) << 1) | (xcd & 1);   // [0,256)
    int qt    = sub >> 3;                // [0,32)
    int ks    = sub & 7;                 // [0,8)

    int t    = threadIdx.x;
    int w    = t >> 6;
    int lane = t & 63;
    int quad = lane >> 4;
    int l15  = lane & 15;
    int q0w  = qt * 128 + w * 32;
    int k0   = ks * 512;

    // resident A fragments: 2 strips of 16 queries x 8 K-steps
    bf16x8 afrag[2][8];
#pragma unroll
    for (int s = 0; s < 2; ++s) {
        const unsigned short* ap =
            aT + ((size_t)(batch * 4096 + q0w + s * 16 + l15)) * 256 + quad * 8;
#pragma unroll
        for (int kk = 0; kk < 8; ++kk)
            afrag[s][kk] = *reinterpret_cast<const bf16x8*>(ap + kk * 32);
    }

    float Z[8], Sx[8], Sy[8], Sm[8];
#pragma unroll
    for (int i = 0; i < 8; ++i) { Z[i] = 0.f; Sx[i] = 0.f; Sy[i] = 0.f; Sm[i] = -1e30f; }

    for (int ch = 0; ch < 8; ++ch) {
        int kbase = k0 + ch * 64;
        const unsigned short* gsrc = bT + ((size_t)(batch * 4096 + kbase)) * 256;
        // stage 64 keys x 512B -> LDS with 544B row stride (bank-balanced)
#pragma unroll
        for (int i = 0; i < 8; ++i) {
            int h = i * 2048 + t * 8;                      // halfword idx in chunk
            uint4 v = *reinterpret_cast<const uint4*>(gsrc + h);
            int key  = i * 8 + (t >> 5);
            int gran = t & 31;
            *reinterpret_cast<uint4*>(&kbuf[key * 272 + gran * 8]) = v;
        }
        __syncthreads();

        float Zc[8];
#pragma unroll
        for (int i = 0; i < 8; ++i) Zc[i] = 0.f;

#pragma unroll
        for (int nt = 0; nt < 4; ++nt) {
            f32x4 acc0 = {0.f, 0.f, 0.f, 0.f};
            f32x4 acc1 = {0.f, 0.f, 0.f, 0.f};
            const unsigned short* lp = &kbuf[(nt * 16 + l15) * 272 + quad * 8];
#pragma unroll
            for (int kk = 0; kk < 8; ++kk) {
                bf16x8 bfrag = *reinterpret_cast<const bf16x8*>(lp + kk * 32);
                acc0 = __builtin_amdgcn_mfma_f32_16x16x32_bf16(afrag[0][kk], bfrag, acc0, 0, 0, 0);
                acc1 = __builtin_amdgcn_mfma_f32_16x16x32_bf16(afrag[1][kk], bfrag, acc1, 0, 0, 0);
            }
            float kx = (float)(nt * 16 + l15);     // key & 63 (kbase is 64-aligned)
#pragma unroll
            for (int r = 0; r < 4; ++r) {
                float p0 = exp2f(acc0[r] * BETA_LOG2E);
                Zc[r]     += p0;  Sx[r]     += p0 * kx;
                Sm[r]      = fmaxf(Sm[r], acc0[r]);
                float p1 = exp2f(acc1[r] * BETA_LOG2E);
                Zc[4 + r] += p1;  Sx[4 + r] += p1 * kx;
                Sm[4 + r]  = fmaxf(Sm[4 + r], acc1[r]);
            }
        }
        float ky = (float)(kbase >> 6);            // constant over the chunk
#pragma unroll
        for (int i = 0; i < 8; ++i) {
            Z[i]  += Zc[i];
            Sy[i]  = fmaf(ky, Zc[i], Sy[i]);
        }
        __syncthreads();
    }

    // reduce across the 16 col-lanes (low 4 lane bits)
#pragma unroll
    for (int i = 0; i < 8; ++i) {
#pragma unroll
        for (int m = 1; m <= 8; m <<= 1) {
            Z[i]  += __shfl_xor(Z[i], m);
            Sx[i] += __shfl_xor(Sx[i], m);
            Sy[i] += __shfl_xor(Sy[i], m);
            Sm[i]  = fmaxf(Sm[i], __shfl_xor(Sm[i], m));
        }
    }
    if (l15 == 0) {
#pragma unroll
        for (int s = 0; s < 2; ++s)
#pragma unroll
            for (int r = 0; r < 4; ++r) {
                int q = q0w + s * 16 + quad * 4 + r;   // C/D row = quad*4+reg
                f32x4 st = {Z[s * 4 + r], Sx[s * 4 + r], Sy[s * 4 + r],
                            exp2f(Sm[s * 4 + r] * BETA_LOG2E)};
                *reinterpret_cast<f32x4*>(&stats[((size_t)(batch * 4096 + q) * 8 + ks) * 4]) = st;
            }
    }
}

// ---------------------------------------------------------------------------
// Kernel 3: merge 8 key-splits, write warp (x,y interleaved) then cert.
// ---------------------------------------------------------------------------
__global__ __launch_bounds__(256) void k_finalize(
    const float* __restrict__ stats, float* __restrict__ out)
{
    int q = blockIdx.x * 256 + threadIdx.x;   // [0, 16384)
    const f32x4* s = reinterpret_cast<const f32x4*>(stats + (size_t)q * 32);
    float Z = 0.f, Sx = 0.f, Sy = 0.f, Pm = 0.f;
#pragma unroll
    for (int k = 0; k < 8; ++k) {
        f32x4 a = s[k];
        Z += a.x; Sx += a.y; Sy += a.z; Pm = fmaxf(Pm, a.w);
    }
    float invZ = 1.0f / Z;
    out[q * 2 + 0]  = Sx * invZ;
    out[q * 2 + 1]  = Sy * invZ;
    out[32768 + q]  = Pm * invZ;
}

extern "C" void kernel_launch(void* const* d_in, const int* in_sizes, int n_in,
                              void* d_out, int out_size, void* d_ws, size_t ws_size,
                              hipStream_t stream)
{
    const float* f0 = (const float*)d_in[0];
    const float* f1 = (const float*)d_in[1];
    unsigned short* aT = (unsigned short*)d_ws;          // 4*4096*256 bf16 = 8 MB
    unsigned short* bT = aT + (size_t)4 * 4096 * 256;    // 8 MB
    float* stats = (float*)(bT + (size_t)4 * 4096 * 256);// 16384*8*4 f32 = 2 MB
    float* out = (float*)d_out;

    hipLaunchKernelGGL(k_norm_transpose, dim3(512),  dim3(256), 0, stream, f0, f1, aT, bT);
    hipLaunchKernelGGL(k_flash,          dim3(1024), dim3(256), 0, stream, aT, bT, stats);
    hipLaunchKernelGGL(k_finalize,       dim3(64),   dim3(256), 0, stream, stats, out);
}

// Round 2
// 159.695 us; speedup vs baseline: 1.0385x; 1.0385x over previous
//
#include <hip/hip_runtime.h>
#include <hip/hip_bf16.h>

#define BETA_LOG2E 14.426950408889634f   // 10 * log2(e)
#define EPSN 1e-6f

typedef __bf16 bf16x8 __attribute__((ext_vector_type(8)));
typedef float  f32x4  __attribute__((ext_vector_type(4)));

static __device__ inline unsigned short f2bf(float f) {
    __hip_bfloat16 h = __float2bfloat16(f);
    return __builtin_bit_cast(unsigned short, h);
}
static __device__ inline float bf2f(unsigned short u) {
    unsigned int b = ((unsigned int)u) << 16;
    return __builtin_bit_cast(float, b);
}

// ---------------------------------------------------------------------------
// Kernel 1 v3: L2-normalize over C, transpose [b][c][n] -> [b][n][c], bf16.
// v2 post-mortem: vectorization alone didn't help -> kernel was latency-bound
// (512 blocks = 2/CU, 16 serialized loads/thread). v3: 1024 blocks (4/CU),
// tile 32n x 256c, 8 x f32x4 loads/thread, 128B-aligned global segments.
// Numerics identical: raw value rounded to bf16, then scaled and re-rounded.
// ---------------------------------------------------------------------------
__global__ __launch_bounds__(256) void k_norm_transpose(
    const float* __restrict__ f0, const float* __restrict__ f1,
    unsigned short* __restrict__ aT, unsigned short* __restrict__ bT)
{
    __shared__ unsigned short tile[32 * 256];  // [n][c] raw bf16
    __shared__ float partial[32][32];          // [cg][n]
    __shared__ float inv_l[32];

    int idx   = blockIdx.x;
    int which = idx >> 9;
    int rem   = idx & 511;
    int b     = rem >> 7;
    int n0    = (rem & 127) * 32;
    const float* src = which ? f1 : f0;
    unsigned short* dst = which ? bT : aT;

    int t  = threadIdx.x;
    int nq = t & 7;     // 8 quads of 4 n  -> 32 n
    int cg = t >> 3;    // 32 groups of 8 c -> 256 c

    const float* sp = src + ((size_t)(b * 256 + cg * 8)) * 4096 + n0 + nq * 4;

    f32x4 ss = {0.f, 0.f, 0.f, 0.f};
    unsigned int pk[4][4];   // [j = n sub-row][4 uints = 8 bf16 over c]
#pragma unroll
    for (int i = 0; i < 8; ++i) {
        f32x4 v = *reinterpret_cast<const f32x4*>(sp + (size_t)i * 4096);
        ss += v * v;
#pragma unroll
        for (int j = 0; j < 4; ++j) {
            unsigned int h = f2bf(v[j]);
            if (i & 1) pk[j][i >> 1] |= h << 16;
            else       pk[j][i >> 1]  = h;
        }
    }
#pragma unroll
    for (int j = 0; j < 4; ++j) {
        int n = nq * 4 + j;
        *reinterpret_cast<uint4*>(&tile[n * 256 + cg * 8]) =
            *reinterpret_cast<const uint4*>(pk[j]);
    }
    *reinterpret_cast<f32x4*>(&partial[cg][nq * 4]) = ss;
    __syncthreads();
    if (t < 32) {
        float s = 0.f;
#pragma unroll
        for (int k = 0; k < 32; ++k) s += partial[k][t];
        inv_l[t] = 1.0f / fmaxf(sqrtf(s), EPSN);
    }
    __syncthreads();

    // write out: each iter covers 8 n rows x 32 blocks of 16B (512B/row)
#pragma unroll
    for (int it = 0; it < 4; ++it) {
        int n  = it * 8 + (t >> 5);
        int cb = t & 31;
        uint4 v = *reinterpret_cast<const uint4*>(&tile[n * 256 + cb * 8]);
        float inv = inv_l[n];
        unsigned int o[4];
#pragma unroll
        for (int k = 0; k < 4; ++k) {
            unsigned int u = (&v.x)[k];
            unsigned short lo = f2bf(bf2f((unsigned short)(u & 0xffffu)) * inv);
            unsigned short hi = f2bf(bf2f((unsigned short)(u >> 16)) * inv);
            o[k] = (unsigned int)lo | ((unsigned int)hi << 16);
        }
        *reinterpret_cast<uint4*>(&dst[((size_t)(b * 4096 + n0 + n)) * 256 + cb * 8]) =
            *reinterpret_cast<const uint4*>(o);
    }
}

// ---------------------------------------------------------------------------
// Kernel 2 v3: flash cosine-sim + softmax stats.
// REVERTED to round-0 geometry: 512 blocks = 4 batch x 32 qt(128q) x 4 ks
// (proven FETCH ~12 MB: per-XCD working set fits L2; 8 splits thrashed it,
// FETCH 183 MB, dur +50%). Kept from round 1: per-chunk Zc -> Sy hoist,
// pre-exp running max Sm. New: T14 async-stage -- issue chunk ch+1's global
// loads after the stage barrier so their latency hides under the MFMA loop.
// stats[q][ks] = {Z, Sx, Sy, Pmax}
// ---------------------------------------------------------------------------
__global__ __launch_bounds__(256) void k_flash(
    const unsigned short* __restrict__ aT, const unsigned short* __restrict__ bT,
    float* __restrict__ stats)
{
    __shared__ unsigned short kbuf[64 * 272];  // 64 keys x 272 halfwords (544 B)

    int idx   = blockIdx.x;
    int xcd   = idx & 7;                 // XCD swizzle: batch -> 2 XCDs
    int batch = xcd >> 1;
    int sub   = ((idx >> 3) << 1) | (xcd & 1);   // [0,128)
    int qt    = sub >> 2;                // [0,32)
    int ks    = sub & 3;                 // [0,4)

    int t    = threadIdx.x;
    int w    = t >> 6;
    int lane = t & 63;
    int quad = lane >> 4;
    int l15  = lane & 15;
    int q0w  = qt * 128 + w * 32;
    int k0   = ks * 1024;

    // resident A fragments: 2 strips of 16 queries x 8 K-steps
    bf16x8 afrag[2][8];
#pragma unroll
    for (int s = 0; s < 2; ++s) {
        const unsigned short* ap =
            aT + ((size_t)(batch * 4096 + q0w + s * 16 + l15)) * 256 + quad * 8;
#pragma unroll
        for (int kk = 0; kk < 8; ++kk)
            afrag[s][kk] = *reinterpret_cast<const bf16x8*>(ap + kk * 32);
    }

    float Z[8], Sx[8], Sy[8], Sm[8];
#pragma unroll
    for (int i = 0; i < 8; ++i) { Z[i] = 0.f; Sx[i] = 0.f; Sy[i] = 0.f; Sm[i] = -1e30f; }

    const unsigned short* gbase = bT + ((size_t)(batch * 4096 + k0)) * 256;

    // T14 prologue: load chunk 0 into registers
    uint4 vld[8];
#pragma unroll
    for (int i = 0; i < 8; ++i)
        vld[i] = *reinterpret_cast<const uint4*>(gbase + i * 2048 + t * 8);

    for (int ch = 0; ch < 16; ++ch) {
        __syncthreads();   // all waves done reading kbuf (previous chunk)
        // stage 64 keys x 512B -> LDS with 544B row stride (bank-balanced)
#pragma unroll
        for (int i = 0; i < 8; ++i) {
            int key  = i * 8 + (t >> 5);
            int gran = t & 31;
            *reinterpret_cast<uint4*>(&kbuf[key * 272 + gran * 8]) = vld[i];
        }
        __syncthreads();

        // issue next chunk's loads now; latency hides under the MFMA loop
        if (ch < 15) {
            const unsigned short* g = gbase + (ch + 1) * 16384;   // 64 keys * 256 hw
#pragma unroll
            for (int i = 0; i < 8; ++i)
                vld[i] = *reinterpret_cast<const uint4*>(g + i * 2048 + t * 8);
        }

        float Zc[8];
#pragma unroll
        for (int i = 0; i < 8; ++i) Zc[i] = 0.f;

#pragma unroll
        for (int nt = 0; nt < 4; ++nt) {
            f32x4 acc0 = {0.f, 0.f, 0.f, 0.f};
            f32x4 acc1 = {0.f, 0.f, 0.f, 0.f};
            const unsigned short* lp = &kbuf[(nt * 16 + l15) * 272 + quad * 8];
#pragma unroll
            for (int kk = 0; kk < 8; ++kk) {
                bf16x8 bfrag = *reinterpret_cast<const bf16x8*>(lp + kk * 32);
                acc0 = __builtin_amdgcn_mfma_f32_16x16x32_bf16(afrag[0][kk], bfrag, acc0, 0, 0, 0);
                acc1 = __builtin_amdgcn_mfma_f32_16x16x32_bf16(afrag[1][kk], bfrag, acc1, 0, 0, 0);
            }
            float kx = (float)(nt * 16 + l15);     // key & 63 (kbase is 64-aligned)
#pragma unroll
            for (int r = 0; r < 4; ++r) {
                float p0 = exp2f(acc0[r] * BETA_LOG2E);
                Zc[r]     += p0;  Sx[r]     += p0 * kx;
                Sm[r]      = fmaxf(Sm[r], acc0[r]);
                float p1 = exp2f(acc1[r] * BETA_LOG2E);
                Zc[4 + r] += p1;  Sx[4 + r] += p1 * kx;
                Sm[4 + r]  = fmaxf(Sm[4 + r], acc1[r]);
            }
        }
        float ky = (float)(ks * 16 + ch);          // (k0 + ch*64) >> 6
#pragma unroll
        for (int i = 0; i < 8; ++i) {
            Z[i]  += Zc[i];
            Sy[i]  = fmaf(ky, Zc[i], Sy[i]);
        }
    }

    // reduce across the 16 col-lanes (low 4 lane bits)
#pragma unroll
    for (int i = 0; i < 8; ++i) {
#pragma unroll
        for (int m = 1; m <= 8; m <<= 1) {
            Z[i]  += __shfl_xor(Z[i], m);
            Sx[i] += __shfl_xor(Sx[i], m);
            Sy[i] += __shfl_xor(Sy[i], m);
            Sm[i]  = fmaxf(Sm[i], __shfl_xor(Sm[i], m));
        }
    }
    if (l15 == 0) {
#pragma unroll
        for (int s = 0; s < 2; ++s)
#pragma unroll
            for (int r = 0; r < 4; ++r) {
                int q = q0w + s * 16 + quad * 4 + r;   // C/D row = quad*4+reg
                f32x4 st = {Z[s * 4 + r], Sx[s * 4 + r], Sy[s * 4 + r],
                            exp2f(Sm[s * 4 + r] * BETA_LOG2E)};
                *reinterpret_cast<f32x4*>(&stats[((size_t)(batch * 4096 + q) * 4 + ks) * 4]) = st;
            }
    }
}

// ---------------------------------------------------------------------------
// Kernel 3: merge 4 key-splits, write warp (x,y interleaved) then cert.
// ---------------------------------------------------------------------------
__global__ __launch_bounds__(256) void k_finalize(
    const float* __restrict__ stats, float* __restrict__ out)
{
    int q = blockIdx.x * 256 + threadIdx.x;   // [0, 16384)
    const f32x4* s = reinterpret_cast<const f32x4*>(stats + (size_t)q * 16);
    f32x4 a0 = s[0], a1 = s[1], a2 = s[2], a3 = s[3];
    float Z  = a0.x + a1.x + a2.x + a3.x;
    float Sx = a0.y + a1.y + a2.y + a3.y;
    float Sy = a0.z + a1.z + a2.z + a3.z;
    float Pm = fmaxf(fmaxf(a0.w, a1.w), fmaxf(a2.w, a3.w));
    float invZ = 1.0f / Z;
    out[q * 2 + 0]  = Sx * invZ;
    out[q * 2 + 1]  = Sy * invZ;
    out[32768 + q]  = Pm * invZ;
}

extern "C" void kernel_launch(void* const* d_in, const int* in_sizes, int n_in,
                              void* d_out, int out_size, void* d_ws, size_t ws_size,
                              hipStream_t stream)
{
    const float* f0 = (const float*)d_in[0];
    const float* f1 = (const float*)d_in[1];
    unsigned short* aT = (unsigned short*)d_ws;          // 4*4096*256 bf16 = 8 MB
    unsigned short* bT = aT + (size_t)4 * 4096 * 256;    // 8 MB
    float* stats = (float*)(bT + (size_t)4 * 4096 * 256);// 16384*4*4 f32 = 1 MB
    float* out = (float*)d_out;

    hipLaunchKernelGGL(k_norm_transpose, dim3(1024), dim3(256), 0, stream, f0, f1, aT, bT);
    hipLaunchKernelGGL(k_flash,          dim3(512),  dim3(256), 0, stream, aT, bT, stats);
    hipLaunchKernelGGL(k_finalize,       dim3(64),   dim3(256), 0, stream, stats, out);
}